// Round 2
// baseline (209.844 us; speedup 1.0000x reference)
//
#include <hip/hip_runtime.h>

// Problem constants (fixed by setup_inputs): B=32, C=256, H=W=64
#define BATCH 32
#define CHAN  256
#define HGT   64
#define WID   64
#define HW    4096   // HGT*WID

// Kernel 1: build per-batch scatter-accumulated bilinear weight map A[b, 0:4096].
// One block per batch. LDS float atomicAdd; conflicts rare & cheap.
// Mean (1/4096) is folded into the map.
__global__ __launch_bounds__(256) void weight_map_kernel(
        const float* __restrict__ offset,   // [B, 2, H, W] fp32
        const float* __restrict__ ts_ptr,   // scalar fp32
        float* __restrict__ A)              // [B, 4096] fp32 (d_ws)
{
    const int b   = blockIdx.x;
    const int tid = threadIdx.x;

    __shared__ float acc[HW];   // 16 KiB
    for (int k = tid; k < HW; k += 256) acc[k] = 0.0f;
    __syncthreads();

    float ts = ts_ptr[0];
    ts = fminf(fmaxf(ts, 0.001f), 0.01f);

    const float* off_y = offset + (size_t)b * 2 * HW;   // offset[b,0]
    const float* off_x = off_y + HW;                    // offset[b,1]

    for (int p = tid; p < HW; p += 256) {
        const int i = p >> 6;
        const int j = p & 63;
        const float dy = off_y[p];
        const float dx = off_x[p];
        // reference: y = clip(i + ts*offset*H, 0, H-1); same eval order (ts*dy)*64
        float y = fminf(fmaxf((float)i + ts * dy * 64.0f, 0.0f), 63.0f);
        float x = fminf(fmaxf((float)j + ts * dx * 64.0f, 0.0f), 63.0f);
        int y0 = (int)floorf(y); y0 = min(max(y0, 0), HGT - 2);
        int x0 = (int)floorf(x); x0 = min(max(x0, 0), WID - 2);
        const float wy = y - (float)y0;
        const float wx = x - (float)x0;
        const int base = (y0 << 6) + x0;
        atomicAdd(&acc[base],           (1.0f - wy) * (1.0f - wx));
        atomicAdd(&acc[base + 1],       (1.0f - wy) * wx);
        atomicAdd(&acc[base + WID],     wy * (1.0f - wx));
        atomicAdd(&acc[base + WID + 1], wy * wx);
    }
    __syncthreads();

    float* Ab = A + (size_t)b * HW;
    const float s = 1.0f / (float)HW;   // fold the mean into the weight map
    for (int k = tid; k < HW; k += 256) Ab[k] = acc[k] * s;
}

// Kernel 2: O[b,c] = dot(A[b,:], data[b,c,:]).  One block per (b,c).
// Plane = 4096 fp32 = 16 KiB, read as float4 (fully coalesced, 16 B/lane).
// A[b] (16 KiB) is reused by 256 consecutive blocks -> L1/L2 resident.
__global__ __launch_bounds__(256) void dot_kernel(
        const float* __restrict__ data,   // [B, C, H, W] fp32
        const float* __restrict__ A,      // [B, 4096] fp32
        float* __restrict__ out)          // [B, C] fp32
{
    const int blk = blockIdx.x;          // = b*CHAN + c
    const int b   = blk >> 8;
    const int tid = threadIdx.x;

    const float* plane = data + (size_t)blk * HW;
    const float* Ab    = A    + (size_t)b   * HW;

    float sum = 0.0f;
    #pragma unroll
    for (int it = 0; it < 4; ++it) {
        const int idx = (it * 256 + tid) * 4;     // 4 fp32 / thread / iter
        const float4 dv = *reinterpret_cast<const float4*>(plane + idx);
        const float4 av = *reinterpret_cast<const float4*>(Ab + idx);
        sum = fmaf(av.x, dv.x, sum);
        sum = fmaf(av.y, dv.y, sum);
        sum = fmaf(av.z, dv.z, sum);
        sum = fmaf(av.w, dv.w, sum);
    }

    // wave-64 shuffle reduce
    #pragma unroll
    for (int off = 32; off > 0; off >>= 1)
        sum += __shfl_down(sum, off, 64);

    __shared__ float wsum[4];
    const int lane = tid & 63;
    const int wv   = tid >> 6;
    if (lane == 0) wsum[wv] = sum;
    __syncthreads();
    if (tid == 0) {
        out[blk] = wsum[0] + wsum[1] + wsum[2] + wsum[3];
    }
}

extern "C" void kernel_launch(void* const* d_in, const int* in_sizes, int n_in,
                              void* d_out, int out_size, void* d_ws, size_t ws_size,
                              hipStream_t stream) {
    const float* data   = (const float*)d_in[0];  // fp32 [32,256,64,64]
    const float* offset = (const float*)d_in[1];  // fp32 [32,2,64,64]
    const float* ts     = (const float*)d_in[2];  // fp32 scalar

    float* A   = (float*)d_ws;   // [32, 4096] fp32 = 512 KiB scratch
    float* out = (float*)d_out;  // [32, 256] fp32

    weight_map_kernel<<<BATCH, 256, 0, stream>>>(offset, ts, A);
    dot_kernel<<<BATCH * CHAN, 256, 0, stream>>>(data, A, out);
}